// Round 1
// baseline (789.677 us; speedup 1.0000x reference)
//
#include <hip/hip_runtime.h>
#include <math.h>

#define IN_C 128

// ---------------- K1: EvolveGCNO GRU step on W0 -> W ----------------
// gi = W0 @ W_ih^T + b_ih ; gh = W0 @ W_hh^T + b_hh ; gates (r,z,n)
// W = (1-z)*tanh(i_n + r*h_n) + z*W0
__global__ void evolve_w(const float* __restrict__ W0,
                         const float* __restrict__ Wih,
                         const float* __restrict__ Whh,
                         const float* __restrict__ bih,
                         const float* __restrict__ bhh,
                         float* __restrict__ W) {
    __shared__ float w0row[IN_C];
    const int i = blockIdx.x;   // row of W0 (batch index)
    const int j = threadIdx.x;  // output column / gate row
    w0row[j] = W0[i * IN_C + j];
    __syncthreads();

    float ir = bih[j], iz = bih[j + IN_C], inn = bih[j + 2 * IN_C];
    float hr = bhh[j], hz = bhh[j + IN_C], hnn = bhh[j + 2 * IN_C];
    const float* wr = &Wih[(size_t)j * IN_C];
    const float* wz = &Wih[(size_t)(j + IN_C) * IN_C];
    const float* wn = &Wih[(size_t)(j + 2 * IN_C) * IN_C];
    const float* ur = &Whh[(size_t)j * IN_C];
    const float* uz = &Whh[(size_t)(j + IN_C) * IN_C];
    const float* un = &Whh[(size_t)(j + 2 * IN_C) * IN_C];
    #pragma unroll 4
    for (int k = 0; k < IN_C; ++k) {
        const float a = w0row[k];
        ir = fmaf(a, wr[k], ir); iz = fmaf(a, wz[k], iz); inn = fmaf(a, wn[k], inn);
        hr = fmaf(a, ur[k], hr); hz = fmaf(a, uz[k], hz); hnn = fmaf(a, un[k], hnn);
    }
    const float r = 1.0f / (1.0f + expf(-(ir + hr)));
    const float z = 1.0f / (1.0f + expf(-(iz + hz)));
    const float cand = tanhf(inn + r * hnn);
    W[i * IN_C + j] = (1.0f - z) * cand + z * w0row[j];
}

// ---------------- K2: degree / dinv ----------------
__global__ void deg_init(float* __restrict__ deg, int n) {
    const int i = blockIdx.x * blockDim.x + threadIdx.x;
    if (i < n) deg[i] = 1.0f;  // self-loop weight
}

__global__ void deg_accum(const int* __restrict__ col, const float* __restrict__ w,
                          float* __restrict__ deg, int E) {
    const int e = blockIdx.x * blockDim.x + threadIdx.x;
    if (e < E) atomicAdd(&deg[col[e]], w[e]);
}

__global__ void deg_to_dinv(float* __restrict__ deg, int n) {
    const int i = blockIdx.x * blockDim.x + threadIdx.x;
    if (i < n) {
        const float d = deg[i];
        deg[i] = (d > 0.0f) ? rsqrtf(fmaxf(d, 1e-30f)) : 0.0f;
    }
}

// ---------------- K3: h = x @ W  (f32, register-tiled) ----------------
// 64 rows x 64 cols per block; 256 threads as 16x16, 4x4 micro-tile each.
#define TM 64
#define TC 64
#define XS_LD 132  // 128 + 4 pad: keeps 16B align, breaks 4-way bank conflict
__global__ __launch_bounds__(256) void gemm_xw(const float* __restrict__ x,
                                               const float* __restrict__ W,
                                               float* __restrict__ h, int n) {
    __shared__ float xs[TM * XS_LD];
    __shared__ float ws[IN_C * TC];
    const int row0 = (blockIdx.x >> 1) * TM;
    const int c0 = (blockIdx.x & 1) * TC;
    const int t = threadIdx.x;

    for (int idx = t; idx < IN_C * TC; idx += 256) {
        const int k = idx >> 6, c = idx & 63;
        ws[idx] = W[k * IN_C + c0 + c];
    }
    for (int idx = t; idx < TM * IN_C; idx += 256) {
        const int r = idx >> 7, k = idx & 127;
        const int row = row0 + r;
        xs[r * XS_LD + k] = (row < n) ? x[(size_t)row * IN_C + k] : 0.0f;
    }
    __syncthreads();

    const int tr = t >> 4, tc = t & 15;
    float4 acc[4];
    #pragma unroll
    for (int ri = 0; ri < 4; ++ri) acc[ri] = make_float4(0.f, 0.f, 0.f, 0.f);

    for (int k4 = 0; k4 < IN_C; k4 += 4) {
        float4 xv[4], wv[4];
        #pragma unroll
        for (int ri = 0; ri < 4; ++ri)
            xv[ri] = *(const float4*)&xs[(4 * tr + ri) * XS_LD + k4];
        #pragma unroll
        for (int kk = 0; kk < 4; ++kk)
            wv[kk] = *(const float4*)&ws[(k4 + kk) * TC + 4 * tc];
        #pragma unroll
        for (int ri = 0; ri < 4; ++ri) {
            const float4 xr = xv[ri];
            acc[ri].x = fmaf(xr.x, wv[0].x, fmaf(xr.y, wv[1].x, fmaf(xr.z, wv[2].x, fmaf(xr.w, wv[3].x, acc[ri].x))));
            acc[ri].y = fmaf(xr.x, wv[0].y, fmaf(xr.y, wv[1].y, fmaf(xr.z, wv[2].y, fmaf(xr.w, wv[3].y, acc[ri].y))));
            acc[ri].z = fmaf(xr.x, wv[0].z, fmaf(xr.y, wv[1].z, fmaf(xr.z, wv[2].z, fmaf(xr.w, wv[3].z, acc[ri].z))));
            acc[ri].w = fmaf(xr.x, wv[0].w, fmaf(xr.y, wv[1].w, fmaf(xr.z, wv[2].w, fmaf(xr.w, wv[3].w, acc[ri].w))));
        }
    }
    #pragma unroll
    for (int ri = 0; ri < 4; ++ri) {
        const int row = row0 + 4 * tr + ri;
        if (row < n) *(float4*)&h[(size_t)row * IN_C + c0 + 4 * tc] = acc[ri];
    }
}

// ---------------- K4a: agg init with self-loop contribution ----------------
__global__ void agg_init(const float* __restrict__ h, const float* __restrict__ dinv,
                         float* __restrict__ agg, int n) {
    const int idx = blockIdx.x * blockDim.x + threadIdx.x;
    if (idx < n * IN_C) {
        const int i = idx >> 7;
        const float dv = dinv[i];
        agg[idx] = dv * dv * h[idx];
    }
}

// ---------------- K4b: edge scatter (atomic) ----------------
__global__ void scatter_edges(const int* __restrict__ rowi, const int* __restrict__ coli,
                              const float* __restrict__ w, const float* __restrict__ dinv,
                              const float* __restrict__ h, float* __restrict__ agg, int E) {
    const int wid = (blockIdx.x * blockDim.x + threadIdx.x) >> 6;
    const int lane = threadIdx.x & 63;
    const int nw = (gridDim.x * blockDim.x) >> 6;
    for (int e = wid; e < E; e += nw) {
        const int r = rowi[e];
        const int c = coli[e];
        const float norm = dinv[r] * w[e] * dinv[c];
        const float2 hv = *(const float2*)&h[(size_t)r * IN_C + 2 * lane];
        atomicAdd(&agg[(size_t)c * IN_C + 2 * lane], norm * hv.x);
        atomicAdd(&agg[(size_t)c * IN_C + 2 * lane + 1], norm * hv.y);
    }
}

// ---------------- K5: out = relu(agg) @ cls_w^T + cls_b ----------------
__global__ void classify(const float* __restrict__ agg, const float* __restrict__ cls_w,
                         const float* __restrict__ cls_b, float* __restrict__ out, int n) {
    const int wid = (blockIdx.x * blockDim.x + threadIdx.x) >> 6;
    const int lane = threadIdx.x & 63;
    if (wid >= n) return;
    const float2 wv = *(const float2*)&cls_w[2 * lane];
    const float2 av = *(const float2*)&agg[(size_t)wid * IN_C + 2 * lane];
    float s = wv.x * fmaxf(av.x, 0.0f) + wv.y * fmaxf(av.y, 0.0f);
    #pragma unroll
    for (int off = 32; off > 0; off >>= 1) s += __shfl_down(s, off);
    if (lane == 0) out[wid] = s + cls_b[0];
}

extern "C" void kernel_launch(void* const* d_in, const int* in_sizes, int n_in,
                              void* d_out, int out_size, void* d_ws, size_t ws_size,
                              hipStream_t stream) {
    const float* x    = (const float*)d_in[0];
    const int*   eidx = (const int*)d_in[1];   // [2, E] int32
    const float* ew   = (const float*)d_in[2];
    const float* W0   = (const float*)d_in[3];
    const float* Wih  = (const float*)d_in[4];
    const float* Whh  = (const float*)d_in[5];
    const float* bih  = (const float*)d_in[6];
    const float* bhh  = (const float*)d_in[7];
    const float* clsw = (const float*)d_in[8];
    const float* clsb = (const float*)d_in[9];
    float* out = (float*)d_out;

    const int n = in_sizes[0] / IN_C;   // 100000
    const int E = in_sizes[2];          // 600000
    const int* rowi = eidx;
    const int* coli = eidx + E;

    float* ws   = (float*)d_ws;
    float* W    = ws;                                  // 16384 floats
    float* dinv = ws + 16384;                          // n floats (deg, then dinv in-place)
    float* h    = ws + 16384 + ((n + 127) & ~127);     // n*128 floats
    float* agg  = h + (size_t)n * IN_C;                // n*128 floats

    // 1. GRU weight evolution
    evolve_w<<<dim3(IN_C), dim3(IN_C), 0, stream>>>(W0, Wih, Whh, bih, bhh, W);
    // 2. degrees -> dinv
    deg_init<<<dim3((n + 255) / 256), dim3(256), 0, stream>>>(dinv, n);
    deg_accum<<<dim3((E + 255) / 256), dim3(256), 0, stream>>>(coli, ew, dinv, E);
    deg_to_dinv<<<dim3((n + 255) / 256), dim3(256), 0, stream>>>(dinv, n);
    // 3. h = x @ W
    const int nRowTiles = (n + TM - 1) / TM;
    gemm_xw<<<dim3(nRowTiles * 2), dim3(256), 0, stream>>>(x, W, h, n);
    // 4. aggregation
    agg_init<<<dim3((n * IN_C + 255) / 256), dim3(256), 0, stream>>>(h, dinv, agg, n);
    scatter_edges<<<dim3(4096), dim3(256), 0, stream>>>(rowi, coli, ew, dinv, h, agg, E);
    // 5. classifier
    classify<<<dim3(((size_t)n * 64 + 255) / 256), dim3(256), 0, stream>>>(agg, clsw, clsb, out, n);
}

// Round 2
// 399.125 us; speedup vs baseline: 1.9785x; 1.9785x over previous
//
#include <hip/hip_runtime.h>
#include <math.h>

#define IN_C 128

// ---------------- K1: EvolveGCNO GRU step on W0 -> W ----------------
__global__ void evolve_w(const float* __restrict__ W0,
                         const float* __restrict__ Wih,
                         const float* __restrict__ Whh,
                         const float* __restrict__ bih,
                         const float* __restrict__ bhh,
                         float* __restrict__ W) {
    __shared__ float w0row[IN_C];
    const int i = blockIdx.x;
    const int j = threadIdx.x;
    w0row[j] = W0[i * IN_C + j];
    __syncthreads();

    float ir = bih[j], iz = bih[j + IN_C], inn = bih[j + 2 * IN_C];
    float hr = bhh[j], hz = bhh[j + IN_C], hnn = bhh[j + 2 * IN_C];
    const float* wr = &Wih[(size_t)j * IN_C];
    const float* wz = &Wih[(size_t)(j + IN_C) * IN_C];
    const float* wn = &Wih[(size_t)(j + 2 * IN_C) * IN_C];
    const float* ur = &Whh[(size_t)j * IN_C];
    const float* uz = &Whh[(size_t)(j + IN_C) * IN_C];
    const float* un = &Whh[(size_t)(j + 2 * IN_C) * IN_C];
    #pragma unroll 4
    for (int k = 0; k < IN_C; ++k) {
        const float a = w0row[k];
        ir = fmaf(a, wr[k], ir); iz = fmaf(a, wz[k], iz); inn = fmaf(a, wn[k], inn);
        hr = fmaf(a, ur[k], hr); hz = fmaf(a, uz[k], hz); hnn = fmaf(a, un[k], hnn);
    }
    const float r = 1.0f / (1.0f + expf(-(ir + hr)));
    const float z = 1.0f / (1.0f + expf(-(iz + hz)));
    const float cand = tanhf(inn + r * hnn);
    W[i * IN_C + j] = (1.0f - z) * cand + z * w0row[j];
}

// ---------------- K2: node init (deg=1 self-loop, counts=0) ----------------
__global__ void init_node(float* __restrict__ deg, int* __restrict__ counts, int n) {
    const int i = blockIdx.x * blockDim.x + threadIdx.x;
    if (i < n) { deg[i] = 1.0f; counts[i] = 0; }
}

// degree accum + destination histogram in one pass
__global__ void deg_hist(const int* __restrict__ col, const float* __restrict__ w,
                         float* __restrict__ deg, int* __restrict__ counts, int E) {
    const int e = blockIdx.x * blockDim.x + threadIdx.x;
    if (e < E) {
        const int c = col[e];
        atomicAdd(&deg[c], w[e]);
        atomicAdd(&counts[c], 1);
    }
}

__global__ void deg_to_dinv(float* __restrict__ deg, int n) {
    const int i = blockIdx.x * blockDim.x + threadIdx.x;
    if (i < n) {
        const float d = deg[i];
        deg[i] = (d > 0.0f) ? rsqrtf(fmaxf(d, 1e-30f)) : 0.0f;
    }
}

// ---------------- K3: exclusive scan of counts -> rowptr (3 kernels) ----------------
__global__ void scan1(const int* __restrict__ counts, int* __restrict__ rowptr,
                      int* __restrict__ partials, int n) {
    __shared__ int s[256];
    const int t = threadIdx.x;
    const int i = blockIdx.x * 256 + t;
    s[t] = (i < n) ? counts[i] : 0;
    __syncthreads();
    #pragma unroll
    for (int off = 1; off < 256; off <<= 1) {
        const int v = (t >= off) ? s[t - off] : 0;
        __syncthreads();
        s[t] += v;
        __syncthreads();
    }
    if (i < n) rowptr[i] = (t == 0) ? 0 : s[t - 1];
    if (t == 255) partials[blockIdx.x] = s[255];
}

__global__ void scan2(int* __restrict__ partials, int* __restrict__ rowptr, int nb, int n) {
    __shared__ int s[512];
    const int t = threadIdx.x;
    s[t] = (t < nb) ? partials[t] : 0;
    __syncthreads();
    #pragma unroll
    for (int off = 1; off < 512; off <<= 1) {
        const int v = (t >= off) ? s[t - off] : 0;
        __syncthreads();
        s[t] += v;
        __syncthreads();
    }
    if (t < nb) partials[t] = (t == 0) ? 0 : s[t - 1];
    if (t == 511) rowptr[n] = s[511];  // total = E
}

__global__ void scan3(int* __restrict__ rowptr, int* __restrict__ cursor,
                      const int* __restrict__ partials, int n) {
    const int i = blockIdx.x * blockDim.x + threadIdx.x;
    if (i < n) {
        const int v = rowptr[i] + partials[blockIdx.x * 256 >> 8];  // partials[blockIdx.x] for 256-blocks
        rowptr[i] = v;
        cursor[i] = v;
    }
}

// ---------------- K4: place edges in destination-sorted order ----------------
__global__ void build_sorted(const int* __restrict__ rowi, const int* __restrict__ coli,
                             const float* __restrict__ w, const float* __restrict__ dinv,
                             int* __restrict__ cursor, int* __restrict__ srcs,
                             float* __restrict__ norms, int E) {
    const int e = blockIdx.x * blockDim.x + threadIdx.x;
    if (e < E) {
        const int r = rowi[e];
        const int c = coli[e];
        const int pos = atomicAdd(&cursor[c], 1);
        srcs[pos] = r;
        norms[pos] = dinv[r] * w[e] * dinv[c];
    }
}

// ---------------- K5: h = x @ W  (f32, register-tiled) ----------------
#define TM 64
#define TC 64
#define XS_LD 132
__global__ __launch_bounds__(256) void gemm_xw(const float* __restrict__ x,
                                               const float* __restrict__ W,
                                               float* __restrict__ h, int n) {
    __shared__ float xs[TM * XS_LD];
    __shared__ float ws[IN_C * TC];
    const int row0 = (blockIdx.x >> 1) * TM;
    const int c0 = (blockIdx.x & 1) * TC;
    const int t = threadIdx.x;

    for (int idx = t; idx < IN_C * TC; idx += 256) {
        const int k = idx >> 6, c = idx & 63;
        ws[idx] = W[k * IN_C + c0 + c];
    }
    for (int idx = t; idx < TM * IN_C; idx += 256) {
        const int r = idx >> 7, k = idx & 127;
        const int row = row0 + r;
        xs[r * XS_LD + k] = (row < n) ? x[(size_t)row * IN_C + k] : 0.0f;
    }
    __syncthreads();

    const int tr = t >> 4, tc = t & 15;
    float4 acc[4];
    #pragma unroll
    for (int ri = 0; ri < 4; ++ri) acc[ri] = make_float4(0.f, 0.f, 0.f, 0.f);

    for (int k4 = 0; k4 < IN_C; k4 += 4) {
        float4 xv[4], wv[4];
        #pragma unroll
        for (int ri = 0; ri < 4; ++ri)
            xv[ri] = *(const float4*)&xs[(4 * tr + ri) * XS_LD + k4];
        #pragma unroll
        for (int kk = 0; kk < 4; ++kk)
            wv[kk] = *(const float4*)&ws[(k4 + kk) * TC + 4 * tc];
        #pragma unroll
        for (int ri = 0; ri < 4; ++ri) {
            const float4 xr = xv[ri];
            acc[ri].x = fmaf(xr.x, wv[0].x, fmaf(xr.y, wv[1].x, fmaf(xr.z, wv[2].x, fmaf(xr.w, wv[3].x, acc[ri].x))));
            acc[ri].y = fmaf(xr.x, wv[0].y, fmaf(xr.y, wv[1].y, fmaf(xr.z, wv[2].y, fmaf(xr.w, wv[3].y, acc[ri].y))));
            acc[ri].z = fmaf(xr.x, wv[0].z, fmaf(xr.y, wv[1].z, fmaf(xr.z, wv[2].z, fmaf(xr.w, wv[3].z, acc[ri].z))));
            acc[ri].w = fmaf(xr.x, wv[0].w, fmaf(xr.y, wv[1].w, fmaf(xr.z, wv[2].w, fmaf(xr.w, wv[3].w, acc[ri].w))));
        }
    }
    #pragma unroll
    for (int ri = 0; ri < 4; ++ri) {
        const int row = row0 + 4 * tr + ri;
        if (row < n) *(float4*)&h[(size_t)row * IN_C + c0 + 4 * tc] = acc[ri];
    }
}

// ---------------- K6: fused gather + self-loop + ReLU + classifier ----------------
// one wave per destination node; lane handles channels {2*lane, 2*lane+1}
__global__ __launch_bounds__(256) void gather_classify(
        const float* __restrict__ h, const float* __restrict__ dinv,
        const int* __restrict__ rowptr, const int* __restrict__ srcs,
        const float* __restrict__ norms, const float* __restrict__ cls_w,
        const float* __restrict__ cls_b, float* __restrict__ out, int n) {
    const int wid = (blockIdx.x * blockDim.x + threadIdx.x) >> 6;
    const int lane = threadIdx.x & 63;
    if (wid >= n) return;

    const float dv = dinv[wid];
    const float2 hself = *(const float2*)&h[(size_t)wid * IN_C + 2 * lane];
    float ax = dv * dv * hself.x;
    float ay = dv * dv * hself.y;

    const int e0 = rowptr[wid];
    const int e1 = rowptr[wid + 1];
    for (int e = e0; e < e1; ++e) {
        const int s = srcs[e];
        const float nm = norms[e];
        const float2 hv = *(const float2*)&h[(size_t)s * IN_C + 2 * lane];
        ax = fmaf(nm, hv.x, ax);
        ay = fmaf(nm, hv.y, ay);
    }

    const float2 wv = *(const float2*)&cls_w[2 * lane];
    float sum = wv.x * fmaxf(ax, 0.0f) + wv.y * fmaxf(ay, 0.0f);
    #pragma unroll
    for (int off = 32; off > 0; off >>= 1) sum += __shfl_down(sum, off);
    if (lane == 0) out[wid] = sum + cls_b[0];
}

extern "C" void kernel_launch(void* const* d_in, const int* in_sizes, int n_in,
                              void* d_out, int out_size, void* d_ws, size_t ws_size,
                              hipStream_t stream) {
    const float* x    = (const float*)d_in[0];
    const int*   eidx = (const int*)d_in[1];   // [2, E] int32
    const float* ew   = (const float*)d_in[2];
    const float* W0   = (const float*)d_in[3];
    const float* Wih  = (const float*)d_in[4];
    const float* Whh  = (const float*)d_in[5];
    const float* bih  = (const float*)d_in[6];
    const float* bhh  = (const float*)d_in[7];
    const float* clsw = (const float*)d_in[8];
    const float* clsb = (const float*)d_in[9];
    float* out = (float*)d_out;

    const int n = in_sizes[0] / IN_C;   // 100000
    const int E = in_sizes[2];          // 600000
    const int* rowi = eidx;
    const int* coli = eidx + E;
    const int nPad = (n + 127) & ~127;

    float* ws   = (float*)d_ws;
    float* W    = ws;                              // 16384
    float* dinv = W + 16384;                       // nPad
    float* h    = dinv + nPad;                     // n*128
    float* norms = h + (size_t)n * IN_C;           // E
    int* rowptr  = (int*)(norms + E);              // n+1
    int* cursor  = rowptr + (n + 1);               // n
    int* counts  = cursor + n;                     // n
    int* srcs    = counts + n;                     // E
    int* partials = srcs + E;                      // up to 512

    const int nb = (n + 255) / 256;  // scan blocks (must be <= 512)

    // 1. GRU weight evolution
    evolve_w<<<dim3(IN_C), dim3(IN_C), 0, stream>>>(W0, Wih, Whh, bih, bhh, W);
    // 2. degrees + histogram
    init_node<<<dim3((n + 255) / 256), dim3(256), 0, stream>>>(dinv, counts, n);
    deg_hist<<<dim3((E + 255) / 256), dim3(256), 0, stream>>>(coli, ew, dinv, counts, E);
    deg_to_dinv<<<dim3((n + 255) / 256), dim3(256), 0, stream>>>(dinv, n);
    // 3. scan counts -> rowptr, cursor
    scan1<<<dim3(nb), dim3(256), 0, stream>>>(counts, rowptr, partials, n);
    scan2<<<dim3(1), dim3(512), 0, stream>>>(partials, rowptr, nb, n);
    scan3<<<dim3(nb), dim3(256), 0, stream>>>(rowptr, cursor, partials, n);
    // 4. destination-sorted edge list with precomputed norms
    build_sorted<<<dim3((E + 255) / 256), dim3(256), 0, stream>>>(rowi, coli, ew, dinv,
                                                                  cursor, srcs, norms, E);
    // 5. h = x @ W
    const int nRowTiles = (n + TM - 1) / TM;
    gemm_xw<<<dim3(nRowTiles * 2), dim3(256), 0, stream>>>(x, W, h, n);
    // 6. fused gather + ReLU + classifier
    gather_classify<<<dim3((n + 3) / 4), dim3(256), 0, stream>>>(h, dinv, rowptr, srcs,
                                                                 norms, clsw, clsb, out, n);
}

// Round 3
// 306.801 us; speedup vs baseline: 2.5739x; 1.3009x over previous
//
#include <hip/hip_runtime.h>
#include <math.h>

#define IN_C 128

typedef short short8 __attribute__((ext_vector_type(8)));
typedef float floatx4 __attribute__((ext_vector_type(4)));

static __device__ __forceinline__ unsigned short f2bf(float f) {
    unsigned int u = __float_as_uint(f);
    u += 0x7fffu + ((u >> 16) & 1u);  // RNE
    return (unsigned short)(u >> 16);
}

// ---------------- K1: EvolveGCNO GRU step on W0 -> W ----------------
__global__ void evolve_w(const float* __restrict__ W0,
                         const float* __restrict__ Wih,
                         const float* __restrict__ Whh,
                         const float* __restrict__ bih,
                         const float* __restrict__ bhh,
                         float* __restrict__ W) {
    __shared__ float w0row[IN_C];
    const int i = blockIdx.x;
    const int j = threadIdx.x;
    w0row[j] = W0[i * IN_C + j];
    __syncthreads();

    float ir = bih[j], iz = bih[j + IN_C], inn = bih[j + 2 * IN_C];
    float hr = bhh[j], hz = bhh[j + IN_C], hnn = bhh[j + 2 * IN_C];
    const float* wr = &Wih[(size_t)j * IN_C];
    const float* wz = &Wih[(size_t)(j + IN_C) * IN_C];
    const float* wn = &Wih[(size_t)(j + 2 * IN_C) * IN_C];
    const float* ur = &Whh[(size_t)j * IN_C];
    const float* uz = &Whh[(size_t)(j + IN_C) * IN_C];
    const float* un = &Whh[(size_t)(j + 2 * IN_C) * IN_C];
    #pragma unroll 4
    for (int k = 0; k < IN_C; ++k) {
        const float a = w0row[k];
        ir = fmaf(a, wr[k], ir); iz = fmaf(a, wz[k], iz); inn = fmaf(a, wn[k], inn);
        hr = fmaf(a, ur[k], hr); hz = fmaf(a, uz[k], hz); hnn = fmaf(a, un[k], hnn);
    }
    const float r = 1.0f / (1.0f + expf(-(ir + hr)));
    const float z = 1.0f / (1.0f + expf(-(iz + hz)));
    const float cand = tanhf(inn + r * hnn);
    W[i * IN_C + j] = (1.0f - z) * cand + z * w0row[j];
}

// convert + transpose evolved W -> bf16, n-major: Wbt[n][k] = W[k][n]
__global__ void w_to_bf16t(const float* __restrict__ W, unsigned short* __restrict__ Wbt) {
    const int t = blockIdx.x * 256 + threadIdx.x;  // 16384 total
    const int nn = t >> 7, k = t & 127;
    Wbt[nn * IN_C + k] = f2bf(W[k * IN_C + nn]);
}

// ---------------- K2: node init + degree/histogram ----------------
__global__ void init_node(float* __restrict__ deg, int* __restrict__ counts, int n) {
    const int i = blockIdx.x * blockDim.x + threadIdx.x;
    if (i < n) { deg[i] = 1.0f; counts[i] = 0; }
}

__global__ void deg_hist(const int* __restrict__ col, const float* __restrict__ w,
                         float* __restrict__ deg, int* __restrict__ counts, int E) {
    const int e = blockIdx.x * blockDim.x + threadIdx.x;
    if (e < E) {
        const int c = col[e];
        atomicAdd(&deg[c], w[e]);
        atomicAdd(&counts[c], 1);
    }
}

__global__ void deg_to_dinv(float* __restrict__ deg, int n) {
    const int i = blockIdx.x * blockDim.x + threadIdx.x;
    if (i < n) {
        const float d = deg[i];
        deg[i] = (d > 0.0f) ? rsqrtf(fmaxf(d, 1e-30f)) : 0.0f;
    }
}

// ---------------- K3: exclusive scan of counts -> rowptr ----------------
__global__ void scan1(const int* __restrict__ counts, int* __restrict__ rowptr,
                      int* __restrict__ partials, int n) {
    __shared__ int s[256];
    const int t = threadIdx.x;
    const int i = blockIdx.x * 256 + t;
    s[t] = (i < n) ? counts[i] : 0;
    __syncthreads();
    #pragma unroll
    for (int off = 1; off < 256; off <<= 1) {
        const int v = (t >= off) ? s[t - off] : 0;
        __syncthreads();
        s[t] += v;
        __syncthreads();
    }
    if (i < n) rowptr[i] = (t == 0) ? 0 : s[t - 1];
    if (t == 255) partials[blockIdx.x] = s[255];
}

__global__ void scan2(int* __restrict__ partials, int* __restrict__ rowptr, int nb, int n) {
    __shared__ int s[512];
    const int t = threadIdx.x;
    s[t] = (t < nb) ? partials[t] : 0;
    __syncthreads();
    #pragma unroll
    for (int off = 1; off < 512; off <<= 1) {
        const int v = (t >= off) ? s[t - off] : 0;
        __syncthreads();
        s[t] += v;
        __syncthreads();
    }
    if (t < nb) partials[t] = (t == 0) ? 0 : s[t - 1];
    if (t == 511) rowptr[n] = s[511];  // total = E
}

__global__ void scan3(int* __restrict__ rowptr, int* __restrict__ cursor,
                      const int* __restrict__ partials, int n) {
    const int i = blockIdx.x * blockDim.x + threadIdx.x;
    if (i < n) {
        const int v = rowptr[i] + partials[blockIdx.x];
        rowptr[i] = v;
        cursor[i] = v;
    }
}

// ---------------- K4: place edges in destination-sorted order ----------------
__global__ void build_sorted(const int* __restrict__ rowi, const int* __restrict__ coli,
                             const float* __restrict__ w, const float* __restrict__ dinv,
                             int* __restrict__ cursor, int* __restrict__ srcs,
                             float* __restrict__ norms, int E) {
    const int e = blockIdx.x * blockDim.x + threadIdx.x;
    if (e < E) {
        const int r = rowi[e];
        const int c = coli[e];
        const int pos = atomicAdd(&cursor[c], 1);
        srcs[pos] = r;
        norms[pos] = dinv[r] * w[e] * dinv[c];
    }
}

// ---------------- K5: h = bf16(x @ W)  via MFMA ----------------
// 128 rows x 128 cols per block, full K=128 in LDS. 4 waves, each 32 rows.
#define ALD 136  // 128 + 8 pad (shorts): breaks row-stride bank aliasing
__global__ __launch_bounds__(256) void gemm_bf16(const float* __restrict__ x,
                                                 const unsigned short* __restrict__ Wbt,
                                                 unsigned short* __restrict__ hb, int n) {
    __shared__ unsigned short As[128 * ALD];
    __shared__ unsigned short Ws[128 * ALD];
    const int t = threadIdx.x;
    const size_t row0 = (size_t)blockIdx.x * 128;

    // stage W^T (bf16, n-major) : 2048 chunks of 8 shorts
    for (int idx = t; idx < 2048; idx += 256) {
        const int nn = idx >> 4, k8 = (idx & 15) * 8;
        *(uint4*)&Ws[nn * ALD + k8] = *(const uint4*)&Wbt[nn * IN_C + k8];
    }
    // stage x tile (f32 -> bf16) : 4096 float4 chunks
    for (int idx = t; idx < 4096; idx += 256) {
        const int r = idx >> 5, c4 = (idx & 31) * 4;
        size_t row = row0 + r;
        if (row >= (size_t)n) row = (size_t)n - 1;  // clamp; OOB rows never stored
        const float4 v = *(const float4*)&x[row * IN_C + c4];
        ushort4 b;
        b.x = f2bf(v.x); b.y = f2bf(v.y); b.z = f2bf(v.z); b.w = f2bf(v.w);
        *(ushort4*)&As[r * ALD + c4] = b;
    }
    __syncthreads();

    const int w = t >> 6, lane = t & 63, ln = lane & 15, quad = lane >> 4;
    floatx4 acc[2][8];
    #pragma unroll
    for (int mt = 0; mt < 2; ++mt)
        #pragma unroll
        for (int nt = 0; nt < 8; ++nt)
            acc[mt][nt] = (floatx4){0.f, 0.f, 0.f, 0.f};

    #pragma unroll
    for (int k0 = 0; k0 < 128; k0 += 32) {
        const short8 a0 = *(const short8*)&As[(w * 32 + ln) * ALD + k0 + quad * 8];
        const short8 a1 = *(const short8*)&As[(w * 32 + 16 + ln) * ALD + k0 + quad * 8];
        #pragma unroll
        for (int nt = 0; nt < 8; ++nt) {
            const short8 b = *(const short8*)&Ws[(nt * 16 + ln) * ALD + k0 + quad * 8];
            acc[0][nt] = __builtin_amdgcn_mfma_f32_16x16x32_bf16(a0, b, acc[0][nt], 0, 0, 0);
            acc[1][nt] = __builtin_amdgcn_mfma_f32_16x16x32_bf16(a1, b, acc[1][nt], 0, 0, 0);
        }
    }

    // D[m = quad*4+reg][nn = nt*16+ln]
    #pragma unroll
    for (int mt = 0; mt < 2; ++mt) {
        #pragma unroll
        for (int reg = 0; reg < 4; ++reg) {
            const size_t row = row0 + w * 32 + mt * 16 + quad * 4 + reg;
            if (row < (size_t)n) {
                #pragma unroll
                for (int nt = 0; nt < 8; ++nt)
                    hb[row * IN_C + nt * 16 + ln] = f2bf(acc[mt][nt][reg]);
            }
        }
    }
}

// ---------------- K6: fused gather + self-loop + ReLU + classifier ----------------
// one wave per destination node; lane handles channels {2*lane, 2*lane+1}
__global__ __launch_bounds__(256) void gather_classify(
        const unsigned short* __restrict__ hb, const float* __restrict__ dinv,
        const int* __restrict__ rowptr, const int* __restrict__ srcs,
        const float* __restrict__ norms, const float* __restrict__ cls_w,
        const float* __restrict__ cls_b, float* __restrict__ out, int n) {
    const int wid = (blockIdx.x * blockDim.x + threadIdx.x) >> 6;
    const int lane = threadIdx.x & 63;
    if (wid >= n) return;

    const float dv = dinv[wid];
    unsigned int hv = *(const unsigned int*)&hb[(size_t)wid * IN_C + 2 * lane];
    float ax = dv * dv * __uint_as_float(hv << 16);
    float ay = dv * dv * __uint_as_float(hv & 0xffff0000u);

    const int e0 = rowptr[wid];
    const int e1 = rowptr[wid + 1];
    for (int e = e0; e < e1; ++e) {
        const int s = srcs[e];
        const float nm = norms[e];
        hv = *(const unsigned int*)&hb[(size_t)s * IN_C + 2 * lane];
        ax = fmaf(nm, __uint_as_float(hv << 16), ax);
        ay = fmaf(nm, __uint_as_float(hv & 0xffff0000u), ay);
    }

    const float2 wv = *(const float2*)&cls_w[2 * lane];
    float sum = wv.x * fmaxf(ax, 0.0f) + wv.y * fmaxf(ay, 0.0f);
    #pragma unroll
    for (int off = 32; off > 0; off >>= 1) sum += __shfl_down(sum, off);
    if (lane == 0) out[wid] = sum + cls_b[0];
}

extern "C" void kernel_launch(void* const* d_in, const int* in_sizes, int n_in,
                              void* d_out, int out_size, void* d_ws, size_t ws_size,
                              hipStream_t stream) {
    const float* x    = (const float*)d_in[0];
    const int*   eidx = (const int*)d_in[1];   // [2, E] int32
    const float* ew   = (const float*)d_in[2];
    const float* W0   = (const float*)d_in[3];
    const float* Wih  = (const float*)d_in[4];
    const float* Whh  = (const float*)d_in[5];
    const float* bih  = (const float*)d_in[6];
    const float* bhh  = (const float*)d_in[7];
    const float* clsw = (const float*)d_in[8];
    const float* clsb = (const float*)d_in[9];
    float* out = (float*)d_out;

    const int n = in_sizes[0] / IN_C;   // 100000
    const int E = in_sizes[2];          // 600000
    const int* rowi = eidx;
    const int* coli = eidx + E;
    const int nPad = (n + 127) & ~127;

    float* ws    = (float*)d_ws;
    float* W     = ws;                              // 16384 f
    float* dinv  = W + 16384;                       // nPad f
    float* norms = dinv + nPad;                     // E f
    int* rowptr  = (int*)(norms + E);               // n+1
    int* cursor  = rowptr + (n + 1);                // n
    int* counts  = cursor + n;                      // n
    int* srcs    = counts + n;                      // E
    int* partials = srcs + E;                       // 512
    unsigned short* hb  = (unsigned short*)(partials + 512);  // n*128 bf16
    unsigned short* Wbt = hb + (size_t)n * IN_C;              // 16384 bf16

    const int nb = (n + 255) / 256;  // scan blocks (must be <= 512)

    // 1. GRU weight evolution + bf16 transpose
    evolve_w<<<dim3(IN_C), dim3(IN_C), 0, stream>>>(W0, Wih, Whh, bih, bhh, W);
    w_to_bf16t<<<dim3(64), dim3(256), 0, stream>>>(W, Wbt);
    // 2. degrees + histogram
    init_node<<<dim3((n + 255) / 256), dim3(256), 0, stream>>>(dinv, counts, n);
    deg_hist<<<dim3((E + 255) / 256), dim3(256), 0, stream>>>(coli, ew, dinv, counts, E);
    deg_to_dinv<<<dim3((n + 255) / 256), dim3(256), 0, stream>>>(dinv, n);
    // 3. scan counts -> rowptr, cursor
    scan1<<<dim3(nb), dim3(256), 0, stream>>>(counts, rowptr, partials, n);
    scan2<<<dim3(1), dim3(512), 0, stream>>>(partials, rowptr, nb, n);
    scan3<<<dim3(nb), dim3(256), 0, stream>>>(rowptr, cursor, partials, n);
    // 4. destination-sorted edge list with precomputed norms
    build_sorted<<<dim3((E + 255) / 256), dim3(256), 0, stream>>>(rowi, coli, ew, dinv,
                                                                  cursor, srcs, norms, E);
    // 5. h = bf16(x @ W) via MFMA
    gemm_bf16<<<dim3((n + 127) / 128), dim3(256), 0, stream>>>(x, Wbt, hb, n);
    // 6. fused gather + ReLU + classifier
    gather_classify<<<dim3((n + 3) / 4), dim3(256), 0, stream>>>(hb, dinv, rowptr, srcs,
                                                                 norms, clsw, clsb, out, n);
}

// Round 4
// 260.840 us; speedup vs baseline: 3.0274x; 1.1762x over previous
//
#include <hip/hip_runtime.h>
#include <math.h>

#define IN_C 128

typedef short short8 __attribute__((ext_vector_type(8)));
typedef float floatx4 __attribute__((ext_vector_type(4)));

static __device__ __forceinline__ unsigned short f2bf(float f) {
    unsigned int u = __float_as_uint(f);
    u += 0x7fffu + ((u >> 16) & 1u);  // RNE
    return (unsigned short)(u >> 16);
}

// ---------------- K1: EvolveGCNO GRU step on W0 -> Wbt (bf16, transposed) ----------------
__global__ void evolve_w(const float* __restrict__ W0,
                         const float* __restrict__ Wih,
                         const float* __restrict__ Whh,
                         const float* __restrict__ bih,
                         const float* __restrict__ bhh,
                         unsigned short* __restrict__ Wbt) {
    __shared__ float w0row[IN_C];
    const int i = blockIdx.x;   // row of W0
    const int j = threadIdx.x;  // col of W
    w0row[j] = W0[i * IN_C + j];
    __syncthreads();

    float ir = bih[j], iz = bih[j + IN_C], inn = bih[j + 2 * IN_C];
    float hr = bhh[j], hz = bhh[j + IN_C], hnn = bhh[j + 2 * IN_C];
    const float* wr = &Wih[(size_t)j * IN_C];
    const float* wz = &Wih[(size_t)(j + IN_C) * IN_C];
    const float* wn = &Wih[(size_t)(j + 2 * IN_C) * IN_C];
    const float* ur = &Whh[(size_t)j * IN_C];
    const float* uz = &Whh[(size_t)(j + IN_C) * IN_C];
    const float* un = &Whh[(size_t)(j + 2 * IN_C) * IN_C];
    #pragma unroll 4
    for (int k = 0; k < IN_C; ++k) {
        const float a = w0row[k];
        ir = fmaf(a, wr[k], ir); iz = fmaf(a, wz[k], iz); inn = fmaf(a, wn[k], inn);
        hr = fmaf(a, ur[k], hr); hz = fmaf(a, uz[k], hz); hnn = fmaf(a, un[k], hnn);
    }
    const float r = 1.0f / (1.0f + expf(-(ir + hr)));
    const float z = 1.0f / (1.0f + expf(-(iz + hz)));
    const float cand = tanhf(inn + r * hnn);
    // W[i][j] -> Wbt[n=j][k=i]
    Wbt[j * IN_C + i] = f2bf((1.0f - z) * cand + z * w0row[j]);
}

// ---------------- K2: degree accum + destination histogram ----------------
__global__ void deg_hist(const int* __restrict__ col, const float* __restrict__ w,
                         float* __restrict__ deg, int* __restrict__ counts, int E) {
    const int e = blockIdx.x * blockDim.x + threadIdx.x;
    if (e < E) {
        const int c = col[e];
        atomicAdd(&deg[c], w[e]);
        atomicAdd(&counts[c], 1);
    }
}

// ---------------- K3: scan (3 phases); scan1 also computes dinv in-place ----------------
__global__ void scan1(const int* __restrict__ counts, int* __restrict__ rowptr,
                      int* __restrict__ partials, float* __restrict__ dinv, int n) {
    __shared__ int s[256];
    const int t = threadIdx.x;
    const int i = blockIdx.x * 256 + t;
    if (i < n) dinv[i] = rsqrtf(dinv[i] + 1.0f);  // deg (incl. self-loop) -> dinv, in place
    s[t] = (i < n) ? counts[i] : 0;
    __syncthreads();
    #pragma unroll
    for (int off = 1; off < 256; off <<= 1) {
        const int v = (t >= off) ? s[t - off] : 0;
        __syncthreads();
        s[t] += v;
        __syncthreads();
    }
    if (i < n) rowptr[i] = (t == 0) ? 0 : s[t - 1];
    if (t == 255) partials[blockIdx.x] = s[255];
}

__global__ void scan2(int* __restrict__ partials, int* __restrict__ rowptr, int nb, int n) {
    __shared__ int s[512];
    const int t = threadIdx.x;
    s[t] = (t < nb) ? partials[t] : 0;
    __syncthreads();
    #pragma unroll
    for (int off = 1; off < 512; off <<= 1) {
        const int v = (t >= off) ? s[t - off] : 0;
        __syncthreads();
        s[t] += v;
        __syncthreads();
    }
    if (t < nb) partials[t] = (t == 0) ? 0 : s[t - 1];
    if (t == 511) rowptr[n] = s[511];
}

__global__ void scan3(int* __restrict__ rowptr, int* __restrict__ cursor,
                      const int* __restrict__ partials, int n) {
    const int i = blockIdx.x * blockDim.x + threadIdx.x;
    if (i < n) {
        const int v = rowptr[i] + partials[blockIdx.x];
        rowptr[i] = v;
        cursor[i] = v;
    }
}

// ---------------- K4: place edges destination-sorted, packed (src, norm) ----------------
__global__ void build_sorted(const int* __restrict__ rowi, const int* __restrict__ coli,
                             const float* __restrict__ w, const float* __restrict__ dinv,
                             int* __restrict__ cursor, uint2* __restrict__ edge_sn, int E) {
    const int e = blockIdx.x * blockDim.x + threadIdx.x;
    if (e < E) {
        const int r = rowi[e];
        const int c = coli[e];
        const int pos = atomicAdd(&cursor[c], 1);
        uint2 p;
        p.x = (unsigned int)r;
        p.y = __float_as_uint(dinv[r] * w[e] * dinv[c]);
        edge_sn[pos] = p;
    }
}

// ---------------- K5: h = bf16(x @ W)  via MFMA ----------------
#define ALD 136  // 128 + 8 shorts pad
__global__ __launch_bounds__(256) void gemm_bf16(const float* __restrict__ x,
                                                 const unsigned short* __restrict__ Wbt,
                                                 unsigned short* __restrict__ hb, int n) {
    __shared__ unsigned short As[128 * ALD];
    __shared__ unsigned short Ws[128 * ALD];
    const int t = threadIdx.x;
    const size_t row0 = (size_t)blockIdx.x * 128;

    for (int idx = t; idx < 2048; idx += 256) {
        const int nn = idx >> 4, k8 = (idx & 15) * 8;
        *(uint4*)&Ws[nn * ALD + k8] = *(const uint4*)&Wbt[nn * IN_C + k8];
    }
    for (int idx = t; idx < 4096; idx += 256) {
        const int r = idx >> 5, c4 = (idx & 31) * 4;
        size_t row = row0 + r;
        if (row >= (size_t)n) row = (size_t)n - 1;
        const float4 v = *(const float4*)&x[row * IN_C + c4];
        ushort4 b;
        b.x = f2bf(v.x); b.y = f2bf(v.y); b.z = f2bf(v.z); b.w = f2bf(v.w);
        *(ushort4*)&As[r * ALD + c4] = b;
    }
    __syncthreads();

    const int w = t >> 6, lane = t & 63, ln = lane & 15, quad = lane >> 4;
    floatx4 acc[2][8];
    #pragma unroll
    for (int mt = 0; mt < 2; ++mt)
        #pragma unroll
        for (int nt = 0; nt < 8; ++nt)
            acc[mt][nt] = (floatx4){0.f, 0.f, 0.f, 0.f};

    #pragma unroll
    for (int k0 = 0; k0 < 128; k0 += 32) {
        const short8 a0 = *(const short8*)&As[(w * 32 + ln) * ALD + k0 + quad * 8];
        const short8 a1 = *(const short8*)&As[(w * 32 + 16 + ln) * ALD + k0 + quad * 8];
        #pragma unroll
        for (int nt = 0; nt < 8; ++nt) {
            const short8 b = *(const short8*)&Ws[(nt * 16 + ln) * ALD + k0 + quad * 8];
            acc[0][nt] = __builtin_amdgcn_mfma_f32_16x16x32_bf16(a0, b, acc[0][nt], 0, 0, 0);
            acc[1][nt] = __builtin_amdgcn_mfma_f32_16x16x32_bf16(a1, b, acc[1][nt], 0, 0, 0);
        }
    }

    #pragma unroll
    for (int mt = 0; mt < 2; ++mt) {
        #pragma unroll
        for (int reg = 0; reg < 4; ++reg) {
            const size_t row = row0 + w * 32 + mt * 16 + quad * 4 + reg;
            if (row < (size_t)n) {
                #pragma unroll
                for (int nt = 0; nt < 8; ++nt)
                    hb[row * IN_C + nt * 16 + ln] = f2bf(acc[mt][nt][reg]);
            }
        }
    }
}

// ---------------- K6: fused gather + self-loop + ReLU + classifier ----------------
// one wave per destination node; lane = channels {2l, 2l+1}; 8 edges in flight
__global__ __launch_bounds__(256) void gather_classify(
        const unsigned short* __restrict__ hb, const float* __restrict__ dinv,
        const int* __restrict__ rowptr, const uint2* __restrict__ edge_sn,
        const float* __restrict__ cls_w, const float* __restrict__ cls_b,
        float* __restrict__ out, int n) {
    const int wid = __builtin_amdgcn_readfirstlane((blockIdx.x * blockDim.x + threadIdx.x) >> 6);
    const int lane = threadIdx.x & 63;
    if (wid >= n) return;

    const float dv = dinv[wid];
    unsigned int hv = *(const unsigned int*)&hb[(size_t)wid * IN_C + 2 * lane];
    float ax = dv * dv * __uint_as_float(hv << 16);
    float ay = dv * dv * __uint_as_float(hv & 0xffff0000u);

    const int e0 = rowptr[wid];
    const int e1 = rowptr[wid + 1];
    const int e1m1 = e1 - 1;
    for (int e = e0; e < e1; e += 8) {
        uint2 p[8];
        #pragma unroll
        for (int i = 0; i < 8; ++i) {
            const int idx = (e + i < e1) ? (e + i) : e1m1;
            p[i] = edge_sn[idx];
        }
        unsigned int hr[8];
        #pragma unroll
        for (int i = 0; i < 8; ++i)
            hr[i] = *(const unsigned int*)&hb[(size_t)p[i].x * IN_C + 2 * lane];
        #pragma unroll
        for (int i = 0; i < 8; ++i) {
            const float nm = (e + i < e1) ? __uint_as_float(p[i].y) : 0.0f;
            ax = fmaf(nm, __uint_as_float(hr[i] << 16), ax);
            ay = fmaf(nm, __uint_as_float(hr[i] & 0xffff0000u), ay);
        }
    }

    const float2 wv = *(const float2*)&cls_w[2 * lane];
    float sum = wv.x * fmaxf(ax, 0.0f) + wv.y * fmaxf(ay, 0.0f);
    #pragma unroll
    for (int off = 32; off > 0; off >>= 1) sum += __shfl_down(sum, off);
    if (lane == 0) out[wid] = sum + cls_b[0];
}

extern "C" void kernel_launch(void* const* d_in, const int* in_sizes, int n_in,
                              void* d_out, int out_size, void* d_ws, size_t ws_size,
                              hipStream_t stream) {
    const float* x    = (const float*)d_in[0];
    const int*   eidx = (const int*)d_in[1];   // [2, E] int32
    const float* ew   = (const float*)d_in[2];
    const float* W0   = (const float*)d_in[3];
    const float* Wih  = (const float*)d_in[4];
    const float* Whh  = (const float*)d_in[5];
    const float* bih  = (const float*)d_in[6];
    const float* bhh  = (const float*)d_in[7];
    const float* clsw = (const float*)d_in[8];
    const float* clsb = (const float*)d_in[9];
    float* out = (float*)d_out;

    const int n = in_sizes[0] / IN_C;   // 100000
    const int E = in_sizes[2];          // 600000
    const int* rowi = eidx;
    const int* coli = eidx + E;
    const int nPad = (n + 127) & ~127;

    // workspace layout (4-byte units)
    float* base   = (float*)d_ws;
    float* dinv   = base;                         // nPad f32 (deg, then dinv in place)
    int* counts   = (int*)(dinv + nPad);          // n   (contiguous after deg for one memset)
    int* rowptr   = counts + n;                   // n+1
    int* cursor   = rowptr + n + 1;               // n
    int* partials = cursor + n;                   // 512
    size_t off = (size_t)((partials + 512) - (int*)base);
    off = (off + 3) & ~(size_t)3;                 // 16 B align
    uint2* edge_sn = (uint2*)((int*)base + off);  // E uint2
    unsigned short* Wbt = (unsigned short*)((int*)base + off + 2 * (size_t)E);  // 16384 bf16
    unsigned short* hb  = Wbt + 16384;            // n*128 bf16

    const int nb = (n + 255) / 256;  // <= 512

    // 1. GRU weight evolution (writes bf16 W^T directly)
    evolve_w<<<dim3(IN_C), dim3(IN_C), 0, stream>>>(W0, Wih, Whh, bih, bhh, Wbt);
    // 2. zero deg + counts in one memset, then histogram
    hipMemsetAsync(dinv, 0, (size_t)(nPad + n) * 4, stream);
    deg_hist<<<dim3((E + 255) / 256), dim3(256), 0, stream>>>(coli, ew, dinv, counts, E);
    // 3. scan counts -> rowptr, cursor (scan1 also finalizes dinv)
    scan1<<<dim3(nb), dim3(256), 0, stream>>>(counts, rowptr, partials, dinv, n);
    scan2<<<dim3(1), dim3(512), 0, stream>>>(partials, rowptr, nb, n);
    scan3<<<dim3(nb), dim3(256), 0, stream>>>(rowptr, cursor, partials, n);
    // 4. destination-sorted packed edge list
    build_sorted<<<dim3((E + 255) / 256), dim3(256), 0, stream>>>(rowi, coli, ew, dinv,
                                                                  cursor, edge_sn, E);
    // 5. h = bf16(x @ W) via MFMA
    gemm_bf16<<<dim3((n + 127) / 128), dim3(256), 0, stream>>>(x, Wbt, hb, n);
    // 6. fused gather + ReLU + classifier
    gather_classify<<<dim3((n + 3) / 4), dim3(256), 0, stream>>>(hb, dinv, rowptr, edge_sn,
                                                                 clsw, clsb, out, n);
}